// Round 5
// baseline (105.173 us; speedup 1.0000x reference)
//
#include <hip/hip_runtime.h>
#include <hip/hip_bf16.h>

#define N_NODES 8192
#define DIN     256
#define DOUT    128
#define NHEAD   2
#define CTOT    256          // NHEAD*DOUT, flat channel dim
#define NWORDS  256          // N_NODES/32 bitmask words per row
#define LRELU_A 0.2f
#define CAPN    96           // max degree (Binomial mean 32, sd 5.7; max over 8k rows ~56)

// bf16 <-> f32 helpers (RNE pack)
__device__ __forceinline__ float bflo(unsigned u) { return __uint_as_float(u << 16); }
__device__ __forceinline__ float bfhi(unsigned u) { return __uint_as_float(u & 0xffff0000u); }
__device__ __forceinline__ unsigned short f2bf(float f) {
    unsigned u = __float_as_uint(f);
    u = (u + 0x7fffu + ((u >> 16) & 1u)) >> 16;
    return (unsigned short)u;
}

// ---------------- fast zero of adj bitmask + S_all ---------------------------
__global__ __launch_bounds__(256) void k_clear(float4* __restrict__ adjp,
                                               float4* __restrict__ sallp) {
    const float4 z = make_float4(0.f, 0.f, 0.f, 0.f);
    int b = blockIdx.x, t = threadIdx.x;
    if (b < 2048) {
        adjp[b * 256 + t] = z;
    } else if (t < 64) {
        sallp[t] = z;
    }
}

// ---------------- adjacency bitmask build (dedup via atomicOr) ----------------
__global__ __launch_bounds__(256) void k_build_adj(const int* __restrict__ ei, int E,
                                                   unsigned int* __restrict__ adjw) {
    int e = blockIdx.x * blockDim.x + threadIdx.x;
    if (e < E) {
        int src = ei[e];
        int dst = ei[E + e];
        atomicOr(&adjw[(size_t)src * NWORDS + (dst >> 5)], 1u << (dst & 31));
    }
}

// ---------------- projection GEMM: hb16[n][c] = bf16(sum_f x[n][f]*W[c][f]) --
#define BM 64
#define BN 64
#define BK 32
__global__ __launch_bounds__(256) void k_gemm(const float* __restrict__ x,
                                              const float* __restrict__ W,
                                              unsigned short* __restrict__ hb16) {
    __shared__ float xs[BK][BM];
    __shared__ float wsm[BK][BN];
    int tid = threadIdx.x;
    int tx = tid & 15, ty = tid >> 4;
    int bn = blockIdx.x * BN;
    int bm = blockIdx.y * BM;
    float acc[4][4] = {};
    int lr = tid >> 3;
    int lk = (tid & 7) * 4;

    for (int k0 = 0; k0 < DIN; k0 += BK) {
        #pragma unroll
        for (int rr = 0; rr < BM; rr += 32) {
            float4 v = *reinterpret_cast<const float4*>(&x[(bm + lr + rr) * DIN + k0 + lk]);
            xs[lk + 0][lr + rr] = v.x; xs[lk + 1][lr + rr] = v.y;
            xs[lk + 2][lr + rr] = v.z; xs[lk + 3][lr + rr] = v.w;
        }
        #pragma unroll
        for (int rr = 0; rr < BN; rr += 32) {
            float4 v = *reinterpret_cast<const float4*>(&W[(bn + lr + rr) * DIN + k0 + lk]);
            wsm[lk + 0][lr + rr] = v.x; wsm[lk + 1][lr + rr] = v.y;
            wsm[lk + 2][lr + rr] = v.z; wsm[lk + 3][lr + rr] = v.w;
        }
        __syncthreads();
        #pragma unroll
        for (int k = 0; k < BK; ++k) {
            float a4[4], b4[4];
            *reinterpret_cast<float4*>(a4) = *reinterpret_cast<const float4*>(&xs[k][ty * 4]);
            *reinterpret_cast<float4*>(b4) = *reinterpret_cast<const float4*>(&wsm[k][tx * 4]);
            #pragma unroll
            for (int i = 0; i < 4; ++i)
                #pragma unroll
                for (int j = 0; j < 4; ++j)
                    acc[i][j] += a4[i] * b4[j];
        }
        __syncthreads();
    }
    #pragma unroll
    for (int i = 0; i < 4; ++i) {
        ushort4 v;
        v.x = f2bf(acc[i][0]); v.y = f2bf(acc[i][1]);
        v.z = f2bf(acc[i][2]); v.w = f2bf(acc[i][3]);
        *reinterpret_cast<ushort4*>(&hb16[(bm + ty * 4 + i) * CTOT + bn + tx * 4]) = v;
    }
}

// ---------------- fused scores + column sum (single hb16 pass) ---------------
// 256 blocks x 32 rows. Lane owns channels lane*4..+3; head = lane>>5.
__global__ __launch_bounds__(256) void k_sc2(const uint2* __restrict__ hb16v,
                                             const float* __restrict__ a,
                                             float* __restrict__ s_src,
                                             float* __restrict__ s_dst,
                                             float* __restrict__ S_all) {
    __shared__ float4 cpart[4][64];
    int t = threadIdx.x, wv = t >> 6, lane = t & 63;
    int head = lane >> 5;
    int cb = (lane & 31) * 4;
    const float4 as4 = *reinterpret_cast<const float4*>(&a[head * 256 + cb]);
    const float4 ad4 = *reinterpret_cast<const float4*>(&a[head * 256 + 128 + cb]);
    int r0 = blockIdx.x * 32 + wv * 8;
    float4 cs = make_float4(0.f, 0.f, 0.f, 0.f);
    for (int r = r0; r < r0 + 8; ++r) {
        uint2 hv = hb16v[r * 64 + lane];
        float f0 = bflo(hv.x), f1 = bfhi(hv.x), f2 = bflo(hv.y), f3 = bfhi(hv.y);
        cs.x += f0; cs.y += f1; cs.z += f2; cs.w += f3;
        float ps = f0 * as4.x + f1 * as4.y + f2 * as4.z + f3 * as4.w;
        float pd = f0 * ad4.x + f1 * ad4.y + f2 * ad4.z + f3 * ad4.w;
        #pragma unroll
        for (int off = 16; off; off >>= 1) {
            ps += __shfl_xor(ps, off);
            pd += __shfl_xor(pd, off);
        }
        if ((lane & 31) == 0) {
            s_src[head * N_NODES + r] = ps;
            s_dst[head * N_NODES + r] = pd;
        }
    }
    cpart[wv][lane] = cs;
    __syncthreads();
    if (t < 64) {
        float4 c0 = cpart[0][t], c1 = cpart[1][t], c2 = cpart[2][t], c3 = cpart[3][t];
        atomicAdd(&S_all[t * 4 + 0], c0.x + c1.x + c2.x + c3.x);
        atomicAdd(&S_all[t * 4 + 1], c0.y + c1.y + c2.y + c3.y);
        atomicAdd(&S_all[t * 4 + 2], c0.z + c1.z + c2.z + c3.z);
        atomicAdd(&S_all[t * 4 + 3], c0.w + c1.w + c2.w + c3.w);
    }
}

// ---------------- fused compact + per-edge weights (wave per row) ------------
__global__ __launch_bounds__(256) void k_cw(const unsigned int* __restrict__ adjw,
                                            const float* __restrict__ s_src,
                                            const float* __restrict__ s_dst,
                                            unsigned short* __restrict__ nbrG,
                                            float* __restrict__ wG0,
                                            float* __restrict__ wG1,
                                            int*   __restrict__ degG,
                                            float* __restrict__ ZG0,
                                            float* __restrict__ ZG1) {
    int t    = threadIdx.x;
    int wv   = t >> 6;
    int lane = t & 63;
    int i    = blockIdx.x * 4 + wv;

    const uint4 wq = reinterpret_cast<const uint4*>(adjw + (size_t)i * NWORDS)[lane];
    int cnt = __popc(wq.x) + __popc(wq.y) + __popc(wq.z) + __popc(wq.w);
    int inc = cnt;
    #pragma unroll
    for (int off = 1; off < 64; off <<= 1) {
        int v = __shfl_up(inc, off);
        if (lane >= off) inc += v;
    }
    int deg = __shfl(inc, 63);
    int pos = inc - cnt;
    int idb = lane * 128;
    float ss0 = s_src[i], ss1 = s_src[N_NODES + i];
    float z0 = 0.f, z1 = 0.f;
    size_t rb = (size_t)i * CAPN;

    unsigned int w; int off;
    #pragma unroll
    for (int q = 0; q < 4; ++q) {
        w   = (q == 0) ? wq.x : (q == 1) ? wq.y : (q == 2) ? wq.z : wq.w;
        off = idb + q * 32;
        while (w) {
            int b = __ffs(w) - 1;
            w &= w - 1;
            if (pos < CAPN) {
                int j = off + b;
                float v0 = ss0 + s_dst[j];
                float v1 = ss1 + s_dst[N_NODES + j];
                float e0 = v0 > 0.f ? v0 : LRELU_A * v0;
                float e1 = v1 > 0.f ? v1 : LRELU_A * v1;
                float w0 = expf(e0) - 1.f;
                float w1 = expf(e1) - 1.f;
                nbrG[rb + pos] = (unsigned short)j;
                wG0[rb + pos]  = w0;
                wG1[rb + pos]  = w1;
                z0 += w0; z1 += w1;
            }
            ++pos;
        }
    }
    #pragma unroll
    for (int o = 32; o; o >>= 1) {
        z0 += __shfl_xor(z0, o);
        z1 += __shfl_xor(z1, o);
    }
    if (lane == 0) {
        degG[i] = deg < CAPN ? deg : CAPN;
        ZG0[i]  = (float)N_NODES + z0;
        ZG1[i]  = (float)N_NODES + z1;
    }
}

// ---------------- attention gather: wave-per-stream, lane owns 4 channels ----
// Block per row i. Wave wv handles neighbors k = wv, wv+4, ...; one wave-load
// (64 lanes x 8B) covers an entire 512B hb16 row. LDS combine, 1 barrier.
__global__ __launch_bounds__(256) void k_attn(const unsigned short* __restrict__ nbrG,
                                              const float* __restrict__ wG0,
                                              const float* __restrict__ wG1,
                                              const int*   __restrict__ degG,
                                              const float* __restrict__ ZG0,
                                              const float* __restrict__ ZG1,
                                              const uint2* __restrict__ hb16v,
                                              const float* __restrict__ S_all,
                                              float* __restrict__ out) {
    __shared__ float4 part[4][64];
    int i = blockIdx.x, t = threadIdx.x, wv = t >> 6, lane = t & 63;
    int deg = degG[i];
    const unsigned short* nb = nbrG + (size_t)i * CAPN;
    const float* w0p = wG0 + (size_t)i * CAPN;
    const float* w1p = wG1 + (size_t)i * CAPN;
    bool h1 = lane >= 32;

    float4 a0 = make_float4(0.f, 0.f, 0.f, 0.f), a1 = a0;
    int k = wv;
    for (; k + 4 < deg; k += 8) {
        int ja = nb[k], jb = nb[k + 4];
        float wa = h1 ? w1p[k] : w0p[k];
        float wb = h1 ? w1p[k + 4] : w0p[k + 4];
        uint2 ha = hb16v[ja * 64 + lane];
        uint2 hb = hb16v[jb * 64 + lane];
        a0.x = fmaf(wa, bflo(ha.x), a0.x); a0.y = fmaf(wa, bfhi(ha.x), a0.y);
        a0.z = fmaf(wa, bflo(ha.y), a0.z); a0.w = fmaf(wa, bfhi(ha.y), a0.w);
        a1.x = fmaf(wb, bflo(hb.x), a1.x); a1.y = fmaf(wb, bfhi(hb.x), a1.y);
        a1.z = fmaf(wb, bflo(hb.y), a1.z); a1.w = fmaf(wb, bfhi(hb.y), a1.w);
    }
    if (k < deg) {
        int j = nb[k];
        float wk = h1 ? w1p[k] : w0p[k];
        uint2 hv = hb16v[j * 64 + lane];
        a0.x = fmaf(wk, bflo(hv.x), a0.x); a0.y = fmaf(wk, bfhi(hv.x), a0.y);
        a0.z = fmaf(wk, bflo(hv.y), a0.z); a0.w = fmaf(wk, bfhi(hv.y), a0.w);
    }
    a0.x += a1.x; a0.y += a1.y; a0.z += a1.z; a0.w += a1.w;
    part[wv][lane] = a0;
    __syncthreads();

    if (t < 64) {
        float4 c0 = part[0][t], c1 = part[1][t], c2 = part[2][t], c3 = part[3][t];
        float4 s;
        s.x = c0.x + c1.x + c2.x + c3.x;
        s.y = c0.y + c1.y + c2.y + c3.y;
        s.z = c0.z + c1.z + c2.z + c3.z;
        s.w = c0.w + c1.w + c2.w + c3.w;
        float4 sa = reinterpret_cast<const float4*>(S_all)[t];
        float rz = 1.f / ((t >= 32) ? ZG1[i] : ZG0[i]);
        float4 o;
        o.x = (sa.x + s.x) * rz; o.y = (sa.y + s.y) * rz;
        o.z = (sa.z + s.z) * rz; o.w = (sa.w + s.w) * rz;
        o.x = o.x > 0.f ? o.x : expm1f(o.x);
        o.y = o.y > 0.f ? o.y : expm1f(o.y);
        o.z = o.z > 0.f ? o.z : expm1f(o.z);
        o.w = o.w > 0.f ? o.w : expm1f(o.w);
        reinterpret_cast<float4*>(out)[i * 64 + t] = o;
    }
}

// ---------------- launch ------------------------------------------------------
extern "C" void kernel_launch(void* const* d_in, const int* in_sizes, int n_in,
                              void* d_out, int out_size, void* d_ws, size_t ws_size,
                              hipStream_t stream) {
    const float* x  = (const float*)d_in[0];
    const float* W  = (const float*)d_in[1];
    const float* a  = (const float*)d_in[2];
    const int*   ei = (const int*)d_in[3];
    int E = in_sizes[3] / 2;
    float* out = (float*)d_out;

    char* ws = (char*)d_ws;
    size_t off = 0;
    auto alloc = [&](size_t bytes) { char* p = ws + off; off += (bytes + 255) & ~(size_t)255; return p; };
    unsigned int*   adjw  = (unsigned int*)  alloc((size_t)N_NODES * NWORDS * 4); // 8 MB
    float*          S_all = (float*)         alloc(CTOT * 4);
    float*          s_src = (float*)         alloc((size_t)NHEAD * N_NODES * 4);
    float*          s_dst = (float*)         alloc((size_t)NHEAD * N_NODES * 4);
    unsigned short* hb16  = (unsigned short*)alloc((size_t)N_NODES * CTOT * 2);  // 4 MB
    unsigned short* nbrG  = (unsigned short*)alloc((size_t)N_NODES * CAPN * 2);
    float*          wG0   = (float*)         alloc((size_t)N_NODES * CAPN * 4);
    float*          wG1   = (float*)         alloc((size_t)N_NODES * CAPN * 4);
    int*            degG  = (int*)           alloc((size_t)N_NODES * 4);
    float*          ZG0   = (float*)         alloc((size_t)N_NODES * 4);
    float*          ZG1   = (float*)         alloc((size_t)N_NODES * 4);

    k_clear<<<2049, 256, 0, stream>>>((float4*)adjw, (float4*)S_all);
    k_build_adj<<<(E + 255) / 256, 256, 0, stream>>>(ei, E, adjw);
    k_gemm<<<dim3(CTOT / BN, N_NODES / BM), 256, 0, stream>>>(x, W, hb16);
    k_sc2<<<256, 256, 0, stream>>>((const uint2*)hb16, a, s_src, s_dst, S_all);
    k_cw<<<N_NODES / 4, 256, 0, stream>>>(adjw, s_src, s_dst, nbrG, wG0, wG1, degG, ZG0, ZG1);
    k_attn<<<N_NODES, 256, 0, stream>>>(nbrG, wG0, wG1, degG, ZG0, ZG1,
                                        (const uint2*)hb16, S_all, out);
}

// Round 6
// 91.079 us; speedup vs baseline: 1.1547x; 1.1547x over previous
//
#include <hip/hip_runtime.h>
#include <hip/hip_bf16.h>

#define N_NODES 8192
#define DIN     256
#define DOUT    128
#define NHEAD   2
#define CTOT    256          // NHEAD*DOUT, flat channel dim
#define NWORDS  256          // N_NODES/32 bitmask words per row
#define LRELU_A 0.2f
#define CAP     512          // max supported degree (actual max ~66)

// bf16 helpers
__device__ __forceinline__ float bf(unsigned short u) {
    return __uint_as_float((unsigned)u << 16);
}
__device__ __forceinline__ unsigned short f2bf(float f) {
    unsigned u = __float_as_uint(f);
    u = (u + 0x7fffu + ((u >> 16) & 1u)) >> 16;
    return (unsigned short)u;
}

// ---------------- fast zero of adj bitmask + S_all ---------------------------
__global__ __launch_bounds__(256) void k_clear(float4* __restrict__ adjp,
                                               float4* __restrict__ sallp) {
    const float4 z = make_float4(0.f, 0.f, 0.f, 0.f);
    int b = blockIdx.x, t = threadIdx.x;
    if (b < 2048) {
        adjp[b * 256 + t] = z;
    } else if (t < 64) {
        sallp[t] = z;
    }
}

// ---------------- adjacency bitmask build (dedup via atomicOr) ----------------
__global__ __launch_bounds__(256) void k_build_adj(const int* __restrict__ ei, int E,
                                                   unsigned int* __restrict__ adjw) {
    int e = blockIdx.x * blockDim.x + threadIdx.x;
    if (e < E) {
        int src = ei[e];
        int dst = ei[E + e];
        atomicOr(&adjw[(size_t)src * NWORDS + (dst >> 5)], 1u << (dst & 31));
    }
}

// ---------------- projection GEMM -> bf16: hb16[n][c] ------------------------
#define BM 64
#define BN 64
#define BK 32
__global__ __launch_bounds__(256) void k_gemm(const float* __restrict__ x,
                                              const float* __restrict__ W,
                                              unsigned short* __restrict__ hb16) {
    __shared__ float xs[BK][BM];
    __shared__ float wsm[BK][BN];
    int tid = threadIdx.x;
    int tx = tid & 15, ty = tid >> 4;
    int bn = blockIdx.x * BN;
    int bm = blockIdx.y * BM;
    float acc[4][4] = {};
    int lr = tid >> 3;
    int lk = (tid & 7) * 4;

    for (int k0 = 0; k0 < DIN; k0 += BK) {
        #pragma unroll
        for (int rr = 0; rr < BM; rr += 32) {
            float4 v = *reinterpret_cast<const float4*>(&x[(bm + lr + rr) * DIN + k0 + lk]);
            xs[lk + 0][lr + rr] = v.x; xs[lk + 1][lr + rr] = v.y;
            xs[lk + 2][lr + rr] = v.z; xs[lk + 3][lr + rr] = v.w;
        }
        #pragma unroll
        for (int rr = 0; rr < BN; rr += 32) {
            float4 v = *reinterpret_cast<const float4*>(&W[(bn + lr + rr) * DIN + k0 + lk]);
            wsm[lk + 0][lr + rr] = v.x; wsm[lk + 1][lr + rr] = v.y;
            wsm[lk + 2][lr + rr] = v.z; wsm[lk + 3][lr + rr] = v.w;
        }
        __syncthreads();
        #pragma unroll
        for (int k = 0; k < BK; ++k) {
            float a4[4], b4[4];
            *reinterpret_cast<float4*>(a4) = *reinterpret_cast<const float4*>(&xs[k][ty * 4]);
            *reinterpret_cast<float4*>(b4) = *reinterpret_cast<const float4*>(&wsm[k][tx * 4]);
            #pragma unroll
            for (int i = 0; i < 4; ++i)
                #pragma unroll
                for (int j = 0; j < 4; ++j)
                    acc[i][j] += a4[i] * b4[j];
        }
        __syncthreads();
    }
    #pragma unroll
    for (int i = 0; i < 4; ++i) {
        ushort4 v;
        v.x = f2bf(acc[i][0]); v.y = f2bf(acc[i][1]);
        v.z = f2bf(acc[i][2]); v.w = f2bf(acc[i][3]);
        *reinterpret_cast<ushort4*>(&hb16[(bm + ty * 4 + i) * CTOT + bn + tx * 4]) = v;
    }
}

// ---------------- per-node scores (bf16 reads) --------------------------------
__global__ __launch_bounds__(256) void k_scores(const unsigned short* __restrict__ hb16,
                                                const float* __restrict__ a,
                                                float* __restrict__ s_src,
                                                float* __restrict__ s_dst) {
    int wid  = (blockIdx.x * 256 + threadIdx.x) >> 6; // pair index
    int lane = threadIdx.x & 63;
    int n = wid >> 1, hh = wid & 1;
    const unsigned short* hrow = &hb16[n * CTOT + hh * DOUT];
    const float* av = &a[hh * 2 * DOUT];
    float h0 = bf(hrow[lane]), h1 = bf(hrow[64 + lane]);
    float ps = h0 * av[lane]       + h1 * av[64 + lane];
    float pd = h0 * av[128 + lane] + h1 * av[192 + lane];
    #pragma unroll
    for (int off = 32; off; off >>= 1) {
        ps += __shfl_xor(ps, off);
        pd += __shfl_xor(pd, off);
    }
    if (lane == 0) {
        s_src[hh * N_NODES + n] = ps;
        s_dst[hh * N_NODES + n] = pd;
    }
}

// ---------------- global column sum S_all[c] = sum_n h[n][c] -----------------
__global__ __launch_bounds__(256) void k_colsum(const unsigned short* __restrict__ hb16,
                                                float* __restrict__ S_all) {
    int t = threadIdx.x;
    int r0 = blockIdx.x * 16;      // grid = 512 blocks
    float s = 0.f;
    for (int r = r0; r < r0 + 16; ++r) s += bf(hb16[r * CTOT + t]);
    atomicAdd(&S_all[t], s);
}

// ---------------- attention row kernel (R2 structure, bf16 gather) -----------
// weights w = exp(leakyrelu(s_i+s_j)) - 1 (max-shift skipped: scores bounded,
// exp fp32-safe), Z = N + sum(w), out = elu((S_all + sum w*h_j) / Z).
__global__ __launch_bounds__(256) void k_attn(const unsigned int* __restrict__ adjw,
                                              const float* __restrict__ s_src,
                                              const float* __restrict__ s_dst,
                                              const unsigned short* __restrict__ hb16,
                                              const float* __restrict__ S_all,
                                              float* __restrict__ out) {
    __shared__ unsigned short nbr[CAP];
    __shared__ float          ew0[CAP];
    __shared__ float          ew1[CAP];
    __shared__ int            wtot[4];
    __shared__ float          zr0[4];
    __shared__ float          zr1[4];

    int i    = blockIdx.x;
    int t    = threadIdx.x;
    int lane = t & 63;
    int wv   = t >> 6;

    // --- neighbor-list compaction: popc + wave scan + cross-wave fixup ---
    unsigned int w = adjw[(size_t)i * NWORDS + t];
    int cnt = __popc(w);
    int inc = cnt;
    #pragma unroll
    for (int off = 1; off < 64; off <<= 1) {
        int v = __shfl_up(inc, off);
        if (lane >= off) inc += v;
    }
    if (lane == 63) wtot[wv] = inc;
    __syncthreads();
    int base = 0;
    #pragma unroll
    for (int q = 0; q < 3; ++q) if (q < wv) base += wtot[q];
    int deg = wtot[0] + wtot[1] + wtot[2] + wtot[3];
    int pos = base + inc - cnt;
    unsigned int ww = w;
    while (ww) {
        int b = __ffs(ww) - 1;
        ww &= ww - 1;
        if (pos < CAP) nbr[pos] = (unsigned short)(t * 32 + b);
        ++pos;
    }
    if (deg > CAP) deg = CAP;
    __syncthreads();

    // --- per-edge weights + Z partial sums (single pass, m=0) ---
    float ss0 = s_src[i], ss1 = s_src[N_NODES + i];
    float z0 = 0.f, z1 = 0.f;
    for (int k = t; k < deg; k += 256) {
        int j = nbr[k];
        float v0 = ss0 + s_dst[j];
        float v1 = ss1 + s_dst[N_NODES + j];
        float e0 = v0 > 0.f ? v0 : LRELU_A * v0;
        float e1 = v1 > 0.f ? v1 : LRELU_A * v1;
        float w0 = expf(e0) - 1.f;
        float w1 = expf(e1) - 1.f;
        ew0[k] = w0; ew1[k] = w1;
        z0 += w0; z1 += w1;
    }
    #pragma unroll
    for (int off = 32; off; off >>= 1) {
        z0 += __shfl_xor(z0, off);
        z1 += __shfl_xor(z1, off);
    }
    if (lane == 0) { zr0[wv] = z0; zr1[wv] = z1; }
    __syncthreads();
    float Z0 = (float)N_NODES + zr0[0] + zr0[1] + zr0[2] + zr0[3];
    float Z1 = (float)N_NODES + zr1[0] + zr1[1] + zr1[2] + zr1[3];

    // --- gather: thread t owns channel t; 4-deep ILP; bf16 loads (2B/lane) ---
    int hh = t >> 7;
    const float* ewh = hh ? ew1 : ew0;
    float Zh = hh ? Z1 : Z0;
    float acc = 0.f;
    int k = 0;
    for (; k + 4 <= deg; k += 4) {
        int j0 = nbr[k], j1 = nbr[k + 1], j2 = nbr[k + 2], j3 = nbr[k + 3];
        float w0 = ewh[k], w1 = ewh[k + 1], w2 = ewh[k + 2], w3 = ewh[k + 3];
        float v0 = bf(hb16[j0 * CTOT + t]);
        float v1 = bf(hb16[j1 * CTOT + t]);
        float v2 = bf(hb16[j2 * CTOT + t]);
        float v3 = bf(hb16[j3 * CTOT + t]);
        acc = fmaf(w0, v0, acc);
        acc = fmaf(w1, v1, acc);
        acc = fmaf(w2, v2, acc);
        acc = fmaf(w3, v3, acc);
    }
    for (; k < deg; ++k)
        acc = fmaf(ewh[k], bf(hb16[nbr[k] * CTOT + t]), acc);

    float o = (S_all[t] + acc) / Zh;
    o = o > 0.f ? o : expm1f(o);           // ELU (alpha=1)
    out[i * CTOT + t] = o;
}

// ---------------- launch ------------------------------------------------------
extern "C" void kernel_launch(void* const* d_in, const int* in_sizes, int n_in,
                              void* d_out, int out_size, void* d_ws, size_t ws_size,
                              hipStream_t stream) {
    const float* x  = (const float*)d_in[0];
    const float* W  = (const float*)d_in[1];
    const float* a  = (const float*)d_in[2];
    const int*   ei = (const int*)d_in[3];
    int E = in_sizes[3] / 2;
    float* out = (float*)d_out;

    char* ws = (char*)d_ws;
    size_t off = 0;
    auto alloc = [&](size_t bytes) { char* p = ws + off; off += (bytes + 255) & ~(size_t)255; return p; };
    unsigned int*   adjw  = (unsigned int*)  alloc((size_t)N_NODES * NWORDS * 4); // 8 MB
    float*          S_all = (float*)         alloc(CTOT * 4);
    float*          s_src = (float*)         alloc((size_t)NHEAD * N_NODES * 4);
    float*          s_dst = (float*)         alloc((size_t)NHEAD * N_NODES * 4);
    unsigned short* hb16  = (unsigned short*)alloc((size_t)N_NODES * CTOT * 2);  // 4 MB

    k_clear<<<2049, 256, 0, stream>>>((float4*)adjw, (float4*)S_all);
    k_build_adj<<<(E + 255) / 256, 256, 0, stream>>>(ei, E, adjw);
    k_gemm<<<dim3(CTOT / BN, N_NODES / BM), 256, 0, stream>>>(x, W, hb16);
    k_scores<<<(N_NODES * NHEAD) / 4, 256, 0, stream>>>(hb16, a, s_src, s_dst);
    k_colsum<<<512, 256, 0, stream>>>(hb16, S_all);
    k_attn<<<N_NODES, 256, 0, stream>>>(adjw, s_src, s_dst, hb16, S_all, out);
}